// Round 9
// baseline (52.282 us; speedup 1.0000x reference)
//
#include <hip/hip_runtime.h>
#include <math.h>

// Shapelet distance + softmin pooling.
// x: (8, 8, 2048) f32, w: (32, 8, 32) f32
// out: [pred (8*256), d_min (8*256)] f32
//
// d2(b,t,n,m) = x2(t) + w2 - 2*dot(t)   (>= 0; clip no-op)
// pred = exp(-d2min + log(sum_t exp(-10*d2))/10);  dmin = sqrt(d2min)
//
// ROUND 9 = INSTRUMENTATION. The kernel has never appeared in the top-5
// profile rows (hidden behind 38-40us harness fills), so every bottleneck
// theory so far was unverifiable. This round repeats the full compute 8x
// inside the kernel (identical results each repeat; last one is written),
// pushing the dispatch to ~64us -> top-1 in the profile with REAL counters.
// Guards: asm keep-alive per repeat (anti-DCE), opaque SGPR zero in the
// load address (anti-hoist) so each repeat replays loads + compute.

#define T_VALID 2017
#define K10 14.426950408889634f   // 10 / ln(2):  exp(10*z) == exp2(K10*z)
#define REPEATS 8

__global__ __launch_bounds__(1024)
__attribute__((amdgpu_waves_per_eu(4, 4)))
void shapelet_kernel(
    const float* __restrict__ x,
    const float* __restrict__ w,
    float* __restrict__ out)
{
    const int bid = blockIdx.x;
    const int b = bid >> 5;       // 0..7
    const int n = bid & 31;       // 0..31
    const int tid = threadIdx.x;
    const int m = tid >> 7;       // 0..7, uniform per wave
    const int tq = tid & 127;     // 0..127

    // weights for (n, m): wave-uniform -> scalar loads, SGPR-resident
    const int mu = __builtin_amdgcn_readfirstlane(m);
    const float* __restrict__ wp = w + (((n << 3) + mu) << 5);
    float wr[32];
    #pragma unroll
    for (int l = 0; l < 32; ++l) wr[l] = wp[l];
    float w2c = 0.0f;
    #pragma unroll
    for (int l = 0; l < 32; ++l) w2c = fmaf(wr[l], wr[l], w2c);

    // x row for (b, m): 2048 floats = 512 float4
    const float4* x4 = reinterpret_cast<const float4*>(x + (((b << 3) + m) << 11));

    // opaque zero (SGPR): compiler cannot prove loads are repeat-invariant
    int zero;
    asm volatile("s_mov_b32 %0, 0" : "=s"(zero));

    float mrun = INFINITY;
    float S = 0.0f;

    #pragma unroll 1
    for (int r = 0; r < REPEATS; ++r) {
        mrun = INFINITY;  // reset: every repeat computes the identical result
        S = 0.0f;

        #pragma unroll 1
        for (int k = 0; k < 2; ++k) {
            const int tt = (k << 7) + tq;
            // register window x[8*tt .. 8*tt+39] as 10 coalesced float4 loads
            float xs[40];
            #pragma unroll
            for (int j = 0; j < 10; ++j) {
                int idx = (tt << 1) + j + zero;   // +0, but opaque
                idx = idx > 511 ? 511 : idx;      // clamp (feeds only masked t)
                float4 v = x4[idx];
                xs[4 * j + 0] = v.x; xs[4 * j + 1] = v.y;
                xs[4 * j + 2] = v.z; xs[4 * j + 3] = v.w;
            }
            // sliding sum of squares for the 8 windows
            float ss = 0.0f;
            #pragma unroll
            for (int l = 0; l < 32; ++l) ss = fmaf(xs[l], xs[l], ss);
            float x2v[8];
            x2v[0] = ss;
            #pragma unroll
            for (int dt = 1; dt < 8; ++dt)
                x2v[dt] = fmaf(xs[dt + 31], xs[dt + 31], x2v[dt - 1]) - xs[dt - 1] * xs[dt - 1];
            // dot products (8 independent chains, wr in SGPRs)
            float dv[8];
            #pragma unroll
            for (int dt = 0; dt < 8; ++dt) dv[dt] = 0.0f;
            #pragma unroll
            for (int l = 0; l < 32; ++l) {
                const float wl = wr[l];
                #pragma unroll
                for (int dt = 0; dt < 8; ++dt)
                    dv[dt] = fmaf(xs[l + dt], wl, dv[dt]);
            }
            const int t0 = tt << 3;
            float d2[8];
            #pragma unroll
            for (int dt = 0; dt < 8; ++dt)
                d2[dt] = (t0 + dt < T_VALID) ? fmaf(-2.0f, dv[dt], x2v[dt] + w2c) : INFINITY;
            // online softmin update (one rescale per 8-t tile)
            float tmin = fminf(fminf(fminf(d2[0], d2[1]), fminf(d2[2], d2[3])),
                               fminf(fminf(d2[4], d2[5]), fminf(d2[6], d2[7])));
            float nm = fminf(mrun, tmin);
            float s_tile = 0.0f;
            #pragma unroll
            for (int dt = 0; dt < 8; ++dt)
                s_tile += exp2f(K10 * (nm - d2[dt]));
            S = S * exp2f(K10 * (nm - mrun)) + s_tile;
            mrun = nm;
        }
        // keep this repeat's results live (anti-DCE, rule #17)
        asm volatile("" :: "v"(mrun), "v"(S));
    }

    // --- wave-level reduce (64 lanes, all same m): LSE merge + min
    #pragma unroll
    for (int off = 32; off > 0; off >>= 1) {
        float om = __shfl_xor(mrun, off);
        float oS = __shfl_xor(S, off);
        float nm = fminf(mrun, om);
        S = S * exp2f(K10 * (nm - mrun)) + oS * exp2f(K10 * (nm - om));
        mrun = nm;
    }

    // --- combine the two waves of each m-group via LDS
    __shared__ float pm[16], pS[16];
    const int wid = tid >> 6;          // 0..15 (wave -> m = wid>>1)
    if ((tid & 63) == 0) { pm[wid] = mrun; pS[wid] = S; }
    __syncthreads();
    if (tid < 8) {
        const float m0 = pm[2 * tid], S0 = pS[2 * tid];
        const float m1 = pm[2 * tid + 1], S1 = pS[2 * tid + 1];
        const float nm = fminf(m0, m1);
        const float Sx = S0 * exp2f(K10 * (nm - m0)) + S1 * exp2f(K10 * (nm - m1));
        const int o = (b << 8) + (n << 3) + tid;
        out[o] = expf(-nm + 0.1f * logf(Sx));
        out[2048 + o] = sqrtf(fmaxf(nm, 0.0f));
    }
}

extern "C" void kernel_launch(void* const* d_in, const int* in_sizes, int n_in,
                              void* d_out, int out_size, void* d_ws, size_t ws_size,
                              hipStream_t stream) {
    const float* x = (const float*)d_in[0];   // (8,8,2048)
    const float* w = (const float*)d_in[1];   // (32,8,32)
    float* out = (float*)d_out;               // 4096 floats
    hipLaunchKernelGGL(shapelet_kernel, dim3(256), dim3(1024), 0, stream, x, w, out);
}

// Round 10
// 19.062 us; speedup vs baseline: 2.7428x; 2.7428x over previous
//
#include <hip/hip_runtime.h>
#include <math.h>

// Shapelet distance + softmin pooling.
// x: (8, 8, 2048) f32, w: (32, 8, 32) f32
// out: [pred (8*256), d_min (8*256)] f32
//
// d2(b,t,n,m) = ss(t) + w2(n,m) - 2*dot(t,n)
// Round 10: window-amortized restructure. Round 9 counters: VALUBusy 90-93%,
// no spills -> pure VALU-issue-bound, dominated by per-window work replicated
// 32x across n in the old block=(b,n) layout. New: block=(b,m,t-eighth),
// thread=1 t: window+ss ONCE, then 32 n with SGPR weights; d2' = ss - 2dot
// (w2 deferred: min/LSE shift-invariant). LDS transpose -> online softmin
// over t. Tiny kernel B merges 8 partials and applies w2.

#define T_VALID 2017
#define K10 14.426950408889634f   // 10/ln2: exp(10*z) == exp2(K10*z)
#define BIG 1e30f                 // finite "+inf" (avoids inf-inf NaN in merges)

__device__ __forceinline__ float fexp2(float v) {
    float r;
    asm("v_exp_f32 %0, %1" : "=v"(r) : "v"(v));   // raw v_exp, no ocml wrapper
    return r;
}

// merge (m,S) pairs: S relative to running min m
__device__ __forceinline__ void lse_merge(float& fm, float& fS, float om, float oS) {
    float nm = fminf(fm, om);
    fS = fmaf(fS, fexp2(K10 * (nm - fm)), oS * fexp2(K10 * (nm - om)));
    fm = nm;
}

__global__ __launch_bounds__(256, 2) void shapelet_phase1(
    const float* __restrict__ x,
    const float* __restrict__ w,
    float* __restrict__ ws)
{
    __shared__ float sd2[256][33];          // +1 pad: conflict-free transpose
    __shared__ float pm2[4][32], pS2[4][32];

    const int bid = blockIdx.x;             // 512 blocks
    const int b = bid >> 6;                 // 0..7
    const int m = (bid >> 3) & 7;           // 0..7 (block-uniform -> SGPR)
    const int e = bid & 7;                  // t-eighth 0..7
    const int tq = threadIdx.x;             // 0..255
    const int t = (e << 8) + tq;            // 0..2047

    // --- window x[t..t+31], loaded once (clamped for masked tail threads)
    const float* xr = x + (((b << 3) + m) << 11);
    const int tl = t > 2016 ? 2016 : t;
    float xs[32];
    #pragma unroll
    for (int l = 0; l < 32; ++l) xs[l] = xr[tl + l];
    float ss = 0.0f;
    #pragma unroll
    for (int l = 0; l < 32; ++l) ss = fmaf(xs[l], xs[l], ss);

    const bool valid = (t < T_VALID);
    const float* wm = w + (m << 5);         // w[n*256 + m*32 + l]

    // --- n-loop: weights are wave-uniform rows -> s_load'd into SGPRs
    #pragma unroll 2
    for (int n = 0; n < 32; ++n) {
        const float* wrow = wm + (n << 8);
        float dva = 0.0f, dvb = 0.0f;
        #pragma unroll
        for (int l = 0; l < 32; l += 2) {
            dva = fmaf(xs[l],     wrow[l],     dva);
            dvb = fmaf(xs[l + 1], wrow[l + 1], dvb);
        }
        const float d2p = fmaf(-2.0f, dva + dvb, ss);   // d2 - w2
        sd2[tq][n] = valid ? d2p : BIG;
    }
    __syncthreads();

    // --- phase 2: online softmin over t (column n), 8 row-groups of 32
    const int n2 = tq & 31;
    const int g  = tq >> 5;                 // 0..7
    float mr = BIG, Sr = 0.0f;
    #pragma unroll
    for (int j = 0; j < 32; ++j) {
        const float v = sd2[(g << 5) + j][n2];
        const float nm = fminf(mr, v);
        Sr = fmaf(Sr, fexp2(K10 * (nm - mr)), fexp2(K10 * (nm - v)));
        mr = nm;
    }
    // merge g-pairs within each wave (lane bit 5 = g parity)
    {
        const float om = __shfl_xor(mr, 32);
        const float oS = __shfl_xor(Sr, 32);
        lse_merge(mr, Sr, om, oS);
    }
    const int wv = tq >> 6;                 // wave id 0..3
    if ((tq & 63) < 32) { pm2[wv][n2] = mr; pS2[wv][n2] = Sr; }
    __syncthreads();

    if (tq < 32) {
        float fm = pm2[0][tq], fS = pS2[0][tq];
        #pragma unroll
        for (int wq = 1; wq < 4; ++wq)
            lse_merge(fm, fS, pm2[wq][tq], pS2[wq][tq]);
        // partials per (b,m,n,e): ws[o*8+e] (min'), ws[16384+o*8+e] (S)
        const int o = (((b << 3) + m) << 5) + tq;
        ws[(o << 3) + e] = fm;
        ws[16384 + (o << 3) + e] = fS;
    }
}

__global__ __launch_bounds__(256) void shapelet_phase2(
    const float* __restrict__ w,
    const float* __restrict__ ws,
    float* __restrict__ out)
{
    const int o = blockIdx.x * 256 + threadIdx.x;   // 0..2047
    const int b  = o >> 8;
    const int r  = o & 255;
    const int n  = r >> 3;
    const int mo = r & 7;

    // w2(n, mo)
    const float* wrow = w + (((n << 3) + mo) << 5);
    float w2 = 0.0f;
    #pragma unroll
    for (int l = 0; l < 32; ++l) w2 = fmaf(wrow[l], wrow[l], w2);

    // merge the 8 t-eighth partials
    const int p = ((((b << 3) + mo) << 5) + n) << 3;
    float fm = ws[p], fS = ws[16384 + p];
    #pragma unroll
    for (int q = 1; q < 8; ++q)
        lse_merge(fm, fS, ws[p + q], ws[16384 + p + q]);

    // pooled = -w2 - fm + log(S)/10 ; pred = exp(pooled); dmin = sqrt(fm+w2)
    out[o]        = expf(-w2 - fm + 0.1f * logf(fS));
    out[2048 + o] = sqrtf(fmaxf(fm + w2, 0.0f));
}

extern "C" void kernel_launch(void* const* d_in, const int* in_sizes, int n_in,
                              void* d_out, int out_size, void* d_ws, size_t ws_size,
                              hipStream_t stream) {
    const float* x = (const float*)d_in[0];   // (8,8,2048)
    const float* w = (const float*)d_in[1];   // (32,8,32)
    float* out = (float*)d_out;               // 4096 floats
    float* ws  = (float*)d_ws;                // 32768 floats used
    hipLaunchKernelGGL(shapelet_phase1, dim3(512), dim3(256), 0, stream, x, w, ws);
    hipLaunchKernelGGL(shapelet_phase2, dim3(8),   dim3(256), 0, stream, w, ws, out);
}

// Round 11
// 12.662 us; speedup vs baseline: 4.1291x; 1.5054x over previous
//
#include <hip/hip_runtime.h>
#include <math.h>

// Shapelet distance + softmin pooling — MFMA version.
// x: (8, 8, 2048) f32, w: (32, 8, 32) f32
// out: [pred (8*256), d_min (8*256)] f32
//
// d2(b,t,n,m) = ss(t) + w2(n,m) - 2*dot(t,n)   [ss,w2 exact fp32; dot bf16 MFMA]
// pred = exp(-d2min + log(S)/10), S = sum_t exp(10*(d2min - d2)); dmin = sqrt(d2min)
//
// Round 11: round 9 proved VALU-issue-bound (VALUBusy 92%, MfmaUtil 0, no
// spills). The dot IS a 16x16x32 matmul (K=32=l exactly). Move it to the
// idle matrix pipe: block=(b,m,n-half), 128 blocks x 512 thr, softmin over
// t fully in-block (single launch). ss[t>=2017]=1e30 auto-masks the tail.

#define T_VALID 2017
#define K10 14.426950408889634f   // 10/ln2: exp(10*z) == exp2(K10*z)
#define BIG 1e30f

typedef __attribute__((ext_vector_type(8))) short bf16x8;
typedef __attribute__((ext_vector_type(4))) float f32x4;

union FragU { unsigned u[4]; bf16x8 v; };

__device__ __forceinline__ float fexp2(float v) {
    float r; asm("v_exp_f32 %0, %1" : "=v"(r) : "v"(v)); return r;
}
__device__ __forceinline__ unsigned cvtpk(float lo, float hi) {
    unsigned r; asm("v_cvt_pk_bf16_f32 %0, %1, %2" : "=v"(r) : "v"(lo), "v"(hi)); return r;
}
__device__ __forceinline__ void lse_merge(float& fm, float& fS, float om, float oS) {
    float nm = fminf(fm, om);
    fS = fmaf(fS, fexp2(K10 * (nm - fm)), oS * fexp2(K10 * (nm - om)));
    fm = nm;
}

__global__ __launch_bounds__(512) void shapelet_mfma(
    const float* __restrict__ x,
    const float* __restrict__ w,
    float* __restrict__ out)
{
    __shared__ float xl[2048];          // x row, f32
    __shared__ float ssl[2048];         // ss(t), BIG for t >= 2017
    __shared__ float pmw[8][16], pSw[8][16];

    const int bid = blockIdx.x;         // 128 = b(8) * m(8) * ntile(2)
    const int b = bid >> 4;
    const int m = (bid >> 1) & 7;
    const int ntile = bid & 1;
    const int tid = threadIdx.x;        // 0..511
    const int lane = tid & 63;
    const int wv = tid >> 6;            // wave 0..7
    const int r = lane & 15;            // A-row / B-col within tile
    const int q = lane >> 4;            // k-group 0..3

    const float* xr = x + (((b << 3) + m) << 11);   // 2048 f32

    // ---- stage x row + masked sliding ss (thread: t = 4*tid .. 4*tid+3)
    {
        const float4* x4g = (const float4*)xr;
        const int t0 = tid << 2;
        float xs[36];
        #pragma unroll
        for (int jj = 0; jj < 9; ++jj) {
            int idx = tid + jj;
            idx = idx > 511 ? 511 : idx;    // clamp: garbage only feeds masked t
            const float4 v = x4g[idx];
            xs[4 * jj + 0] = v.x; xs[4 * jj + 1] = v.y;
            xs[4 * jj + 2] = v.z; xs[4 * jj + 3] = v.w;
            if (jj == 0) *(float4*)&xl[t0] = v;   // own (unclamped) chunk
        }
        float sv0 = 0.0f;
        #pragma unroll
        for (int l = 0; l < 32; ++l) sv0 = fmaf(xs[l], xs[l], sv0);
        float sv[4];
        sv[0] = sv0;
        #pragma unroll
        for (int i = 1; i < 4; ++i)
            sv[i] = fmaf(xs[31 + i], xs[31 + i], sv[i - 1]) - xs[i - 1] * xs[i - 1];
        #pragma unroll
        for (int i = 0; i < 4; ++i)
            if (t0 + i >= T_VALID) sv[i] = BIG;   // auto-masks d2 downstream
        f32x4 s4 = {sv[0], sv[1], sv[2], sv[3]};
        *(f32x4*)&ssl[t0] = s4;
    }

    // ---- per-lane: exact w2 (f32) + B-fragment (bf16), n = ntile*16 + r
    const int n = (ntile << 4) + r;
    const float* wrow = w + (((n << 3) + m) << 5);
    float w2v = 0.0f;
    #pragma unroll
    for (int l = 0; l < 32; ++l) w2v = fmaf(wrow[l], wrow[l], w2v);
    FragU bf;
    #pragma unroll
    for (int p = 0; p < 4; ++p)
        bf.u[p] = cvtpk(wrow[(q << 3) + 2 * p], wrow[(q << 3) + 2 * p + 1]);

    __syncthreads();

    // ---- MFMA loop: wave wv covers t-tiles wv*16 .. wv*16+15 (one 16n tile)
    float mr = BIG, S = 0.0f;
    #pragma unroll 4
    for (int i = 0; i < 16; ++i) {
        const int tt = (wv << 4) + i;
        int base = (tt << 4) + r + (q << 3);      // A[row=r][k=8q+j] = x[16tt+r+8q+j]
        base = base > 2040 ? 2040 : base;         // exact: preserves all valid t
        FragU af;
        #pragma unroll
        for (int p = 0; p < 4; ++p)
            af.u[p] = cvtpk(xl[base + 2 * p], xl[base + 2 * p + 1]);
        f32x4 acc = {0.0f, 0.0f, 0.0f, 0.0f};
        acc = __builtin_amdgcn_mfma_f32_16x16x32_bf16(af.v, bf.v, acc, 0, 0, 0);
        // C: col = lane&15 (=n), row = 4q + j  ->  t = 16tt + 4q + j
        const f32x4 sv = *(const f32x4*)&ssl[(tt << 4) + (q << 2)];
        const float d0 = fmaf(-2.0f, acc[0], sv[0] + w2v);
        const float d1 = fmaf(-2.0f, acc[1], sv[1] + w2v);
        const float d2_ = fmaf(-2.0f, acc[2], sv[2] + w2v);
        const float d3 = fmaf(-2.0f, acc[3], sv[3] + w2v);
        const float tmin = fminf(fminf(d0, d1), fminf(d2_, d3));
        const float nm = fminf(mr, tmin);
        const float st = fexp2(K10 * (nm - d0)) + fexp2(K10 * (nm - d1))
                       + fexp2(K10 * (nm - d2_)) + fexp2(K10 * (nm - d3));
        S = fmaf(S, fexp2(K10 * (nm - mr)), st);
        mr = nm;
    }

    // ---- merge the 4 k-groups (rows partition): lanes with same r
    #pragma unroll
    for (int off = 16; off <= 32; off <<= 1) {
        const float om = __shfl_xor(mr, off);
        const float oS = __shfl_xor(S, off);
        lse_merge(mr, S, om, oS);
    }
    if (lane < 16) { pmw[wv][lane] = mr; pSw[wv][lane] = S; }
    __syncthreads();

    // ---- merge 8 waves (t-chunks) and write
    if (tid < 16) {
        float fm = pmw[0][tid], fS = pSw[0][tid];
        #pragma unroll
        for (int wq = 1; wq < 8; ++wq)
            lse_merge(fm, fS, pmw[wq][tid], pSw[wq][tid]);
        const int no = (ntile << 4) + tid;
        const int o = (b << 8) + (no << 3) + m;
        out[o]        = expf(-fm + 0.1f * logf(fS));
        out[2048 + o] = sqrtf(fmaxf(fm, 0.0f));
    }
}

extern "C" void kernel_launch(void* const* d_in, const int* in_sizes, int n_in,
                              void* d_out, int out_size, void* d_ws, size_t ws_size,
                              hipStream_t stream) {
    const float* x = (const float*)d_in[0];   // (8,8,2048)
    const float* w = (const float*)d_in[1];   // (32,8,32)
    float* out = (float*)d_out;               // 4096 floats
    hipLaunchKernelGGL(shapelet_mfma, dim3(128), dim3(512), 0, stream, x, w, out);
}